// Round 7
// baseline (459.565 us; speedup 1.0000x reference)
//
#include <hip/hip_runtime.h>
#include <hip/hip_bf16.h>
#include <hip/hip_cooperative_groups.h>
#include <cstdint>

namespace cg = cooperative_groups;

// Problem constants
#define B_ 4
#define S_ 4096
#define D_ 1024
#define DFF_ 4096
#define KSEL_ 2048
#define M_ (B_ * KSEL_)      // 8192 selected rows total
#define NTOK_ (B_ * S_)      // 16384

typedef short bf16x8 __attribute__((ext_vector_type(8)));
typedef float f32x4 __attribute__((ext_vector_type(4)));

__device__ inline unsigned short f2bf(float f) {
    union { float f; unsigned int u; } c; c.f = f;
    unsigned int u = c.u;
    unsigned int r = u + 0x7fffu + ((u >> 16) & 1u);
    return (unsigned short)(r >> 16);
}

// ---------------------------------------------------------------------------
// Prep: fused weight transposes + router (independent work, one launch).
// blocks [0,4096):      W1 [1024][4096] -> W1T [4096][1024] bf16
// blocks [4096,8192):   W2 [4096][1024] -> W2T [1024][4096] bf16
// blocks [8192,12288):  router: logits = x@Wr, xb = bf16(x), out = x
// ---------------------------------------------------------------------------
__global__ __launch_bounds__(256)
void prep_kernel(const float* __restrict__ W1, unsigned short* __restrict__ W1T,
                 const float* __restrict__ W2, unsigned short* __restrict__ W2T,
                 const float* __restrict__ x, const float* __restrict__ Wr,
                 float* __restrict__ logits, unsigned short* __restrict__ xb,
                 float* __restrict__ out) {
    __shared__ float tile[32][33];
    const int blk = blockIdx.x;
    const int tid = threadIdx.x;
    if (blk < 8192) {
        // transpose part
        const float* src; unsigned short* dst; int R, C, c0, r0;
        if (blk < 4096) {
            int bx = blk & 127, by = blk >> 7;
            src = W1; dst = W1T; R = D_; C = DFF_;
            c0 = bx * 32; r0 = by * 32;
        } else {
            int t = blk - 4096;
            int bx = t & 127, by = t >> 7;
            src = W2; dst = W2T; R = DFF_; C = D_;
            c0 = by * 32; r0 = bx * 32;
        }
        int tx = tid & 31, ty = tid >> 5;   // 32 x 8
        for (int i = ty; i < 32; i += 8)
            tile[i][tx] = src[(size_t)(r0 + i) * C + c0 + tx];
        __syncthreads();
        for (int i = ty; i < 32; i += 8)
            dst[(size_t)(c0 + i) * R + r0 + tx] = f2bf(tile[tx][i]);
    } else {
        // router part: 4 rows per block, one wave per row
        int rb = blk - 8192;
        int wid = tid >> 6, lane = tid & 63;
        int row = rb * 4 + wid;
        const float* xr = x + (size_t)row * D_;
        unsigned short* xbr = xb + (size_t)row * D_;
        float* outr = out + (size_t)row * D_;
        float acc = 0.f;
#pragma unroll
        for (int j = 0; j < 4; j++) {
            int off = j * 256 + lane * 4;
            float4 v = *(const float4*)(xr + off);
            float4 w = *(const float4*)(Wr + off);
            acc += v.x * w.x + v.y * w.y + v.z * w.z + v.w * w.w;
            *(float4*)(outr + off) = v;
            ushort4 o;
            o.x = f2bf(v.x); o.y = f2bf(v.y); o.z = f2bf(v.z); o.w = f2bf(v.w);
            *(ushort4*)(xbr + off) = o;
        }
#pragma unroll
        for (int s = 32; s; s >>= 1) acc += __shfl_xor(acc, s);
        if (lane == 0) logits[row] = acc;
    }
}

// ---------------------------------------------------------------------------
// Cooperative selection kernel: 512 blocks = b(4) x ichunk(16) x jchunk(8).
// Phase 1: partial rank (atomicAdd) — rank_i = #{l_j > l_i} + ties by index.
// Phase 2 (jc==0): per-segment selected count + softmax denom (no max-shift:
//   logits ~N(0,1), exp safe), init loss slot.
// Phase 3 (jc==0): parallel compaction via ballot prefix (ascending index
//   order preserved) + BCE aux loss (flat-index-union targets).
// ---------------------------------------------------------------------------
__global__ __launch_bounds__(256)
void select_coop(const float* __restrict__ logits, int* __restrict__ rank,
                 float* __restrict__ bsum, int* __restrict__ segcnt,
                 int* __restrict__ rowidx, float* __restrict__ rw,
                 float* __restrict__ lossout) {
    cg::grid_group grid = cg::this_grid();
    __shared__ float lj[512];
    __shared__ float redf[256];
    __shared__ int redi[4];
    const int tid = threadIdx.x;
    const int blk = blockIdx.x;
    const int b  = blk >> 7;
    const int ic = (blk >> 3) & 15;
    const int jc = blk & 7;
    const float* L = logits + b * S_;

    // ---- phase 1: partial rank over j-chunk ----
    if (blk == 0 && tid < 4) bsum[tid] = 0.f;
    for (int t = tid; t < 512; t += 256) lj[t] = L[jc * 512 + t];
    __syncthreads();
    const int i = ic * 256 + tid;
    const float li = L[i];
    const int jbase = jc * 512;
    int r = 0;
    const float4* lj4 = (const float4*)lj;
#pragma unroll 4
    for (int q = 0; q < 128; q++) {
        float4 v = lj4[q];
        int jb = jbase + q * 4;
        r += (v.x > li) | ((v.x == li) & (jb     < i));
        r += (v.y > li) | ((v.y == li) & (jb + 1 < i));
        r += (v.z > li) | ((v.z == li) & (jb + 2 < i));
        r += (v.w > li) | ((v.w == li) & (jb + 3 < i));
    }
    atomicAdd(&rank[b * S_ + i], r);

    grid.sync();

    // ---- phase 2: segment counts + softmax denominator ----
    int sel = 0;
    float e = 0.f;
    const int lane = tid & 63, wv = tid >> 6;
    if (jc == 0) {
        sel = rank[b * S_ + i] < KSEL_;
        e = sel ? __expf(li) : 0.f;
        redf[tid] = e; __syncthreads();
        for (int s = 128; s; s >>= 1) {
            if (tid < s) redf[tid] += redf[tid + s];
            __syncthreads();
        }
        if (tid == 0) atomicAdd(&bsum[b], redf[0]);
        unsigned long long mask = __ballot(sel);
        if (lane == 0) redi[wv] = __popcll(mask);
        __syncthreads();
        if (tid == 0) segcnt[b * 16 + ic] = redi[0] + redi[1] + redi[2] + redi[3];
        if (b == 0 && ic == 0 && tid == 0) lossout[0] = 0.f;
    }

    grid.sync();

    // ---- phase 3: scatter + aux loss ----
    if (jc == 0) {
        int segoff = 0;
        for (int k = 0; k < ic; k++) segoff += segcnt[b * 16 + k];
        unsigned long long mask = __ballot(sel);
        if (lane == 0) redi[wv] = __popcll(mask);
        __syncthreads();
        int woff = 0;
        for (int k = 0; k < wv; k++) woff += redi[k];
        int before = __popcll(mask & ((1ull << lane) - 1ull));
        if (sel) {
            int pos = segoff + woff + before;
            rowidx[b * KSEL_ + pos] = b * S_ + i;
            rw[b * KSEL_ + pos] = e / bsum[b];
        }
        // loss over flat index fi
        int fi = (b * 16 + ic) * 256 + tid;
        float l = logits[fi];
        float t = 0.f;
        if (fi < S_)
            t = ((rank[fi] < KSEL_) | (rank[S_ + fi] < KSEL_) |
                 (rank[2 * S_ + fi] < KSEL_) | (rank[3 * S_ + fi] < KSEL_)) ? 1.f : 0.f;
        float v = fmaxf(l, 0.f) - l * t + log1pf(expf(-fabsf(l)));
        redf[tid] = v; __syncthreads();
        for (int s = 128; s; s >>= 1) {
            if (tid < s) redf[tid] += redf[tid + s];
            __syncthreads();
        }
        if (tid == 0) atomicAdd(lossout, redf[0] * (1.f / (float)NTOK_));
    }
}

// ---------------------------------------------------------------------------
// GEMM (m97 structure, round-5 proven): C[M][N] = A(bf16, row-gathered for
// MODE 1) @ B, BT[N][K] K-contiguous. 128x128 tile, BK=64, 4 waves x 64x64.
// global_load_lds width=16, XOR chunk swizzle. XCD-locality: tile_m along
// blockIdx.x (gridDim.x = 64, multiple of 8) so A-tile sharers land on the
// same XCD L2. Epilogue: acc -> Cs (separate LDS, 32x132 f32) in 4 passes ->
// coalesced 16B stores. MODE 1: H = silu(A@W1) bf16.
// MODE 2: Out[row] = x[row] + (H@W2)*rw (f32 scatter).
// ---------------------------------------------------------------------------
template <int MODE>
__global__ __launch_bounds__(256)
void gemm_bt_kernel(const unsigned short* __restrict__ A,
                    const unsigned short* __restrict__ BT,
                    const int* __restrict__ rowidx,
                    const float* __restrict__ rw,
                    const float* __restrict__ x,
                    unsigned short* __restrict__ Hout,
                    float* __restrict__ Out,
                    int K, int N) {
    __shared__ __attribute__((aligned(16))) unsigned short As[128 * 64];  // 16 KB
    __shared__ __attribute__((aligned(16))) unsigned short Bs[128 * 64];  // 16 KB
    __shared__ __attribute__((aligned(16))) float Cs[32 * 132];           // 16.5 KB
    const int tid = threadIdx.x;
    const int w = tid >> 6, lane = tid & 63;
    const int wm = w >> 1, wn = w & 1;
    const int tile_m = blockIdx.x * 128;
    const int tile_n = blockIdx.y * 128;

    const int srow = lane >> 3;
    const int sw = (lane & 7) ^ srow;
    const uint64_t abase = (uint64_t)(uintptr_t)A;
    const uint64_t bbase = (uint64_t)(uintptr_t)BT;
    uint64_t aaddr[4], baddr[4];
#pragma unroll
    for (int t = 0; t < 4; ++t) {
        int r = t * 32 + w * 8 + srow;
        int am = tile_m + r;
        int ar = (MODE == 1) ? rowidx[am] : am;
        aaddr[t] = abase + ((uint64_t)ar * K + (uint64_t)sw * 8) * 2ull;
        int bn = tile_n + r;
        baddr[t] = bbase + ((uint64_t)bn * K + (uint64_t)sw * 8) * 2ull;
    }

    f32x4 acc[4][4];
#pragma unroll
    for (int i = 0; i < 4; i++)
#pragma unroll
        for (int j = 0; j < 4; j++) acc[i][j] = (f32x4){0.f, 0.f, 0.f, 0.f};

    const int lr = lane & 15, quad = lane >> 4;
    const int KI = K >> 6;
    for (int it = 0; it < KI; ++it) {
        const uint64_t koff = (uint64_t)(it * 64) * 2ull;
#pragma unroll
        for (int t = 0; t < 4; ++t) {
            unsigned short* ldsA = &As[(t * 32 + w * 8) * 64];
            unsigned short* ldsB = &Bs[(t * 32 + w * 8) * 64];
            __builtin_amdgcn_global_load_lds(
                (const __attribute__((address_space(1))) unsigned int*)(uintptr_t)(aaddr[t] + koff),
                (__attribute__((address_space(3))) unsigned int*)ldsA, 16, 0, 0);
            __builtin_amdgcn_global_load_lds(
                (const __attribute__((address_space(1))) unsigned int*)(uintptr_t)(baddr[t] + koff),
                (__attribute__((address_space(3))) unsigned int*)ldsB, 16, 0, 0);
        }
        __syncthreads();
#pragma unroll
        for (int ks = 0; ks < 2; ++ks) {
            bf16x8 af[4], bfr[4];
#pragma unroll
            for (int t4 = 0; t4 < 4; ++t4) {
                int row = wm * 64 + t4 * 16 + lr;
                int kc = ks * 4 + quad;
                af[t4] = *(const bf16x8*)((const char*)As + row * 128 + ((kc ^ (lr & 7)) * 16));
                int nr = wn * 64 + t4 * 16 + lr;
                bfr[t4] = *(const bf16x8*)((const char*)Bs + nr * 128 + ((kc ^ (lr & 7)) * 16));
            }
#pragma unroll
            for (int ti = 0; ti < 4; ++ti)
#pragma unroll
                for (int tj = 0; tj < 4; ++tj)
                    acc[ti][tj] = __builtin_amdgcn_mfma_f32_16x16x32_bf16(
                        af[ti], bfr[tj], acc[ti][tj], 0, 0, 0);
        }
        __syncthreads();
    }

    const int erow = tid >> 3, eseg = tid & 7;
#pragma unroll
    for (int p = 0; p < 4; ++p) {
        if (p) __syncthreads();
        if (wm == (p >> 1)) {
#pragma unroll
            for (int t = 0; t < 2; ++t) {
                int ti = (p & 1) * 2 + t;
#pragma unroll
                for (int tj = 0; tj < 4; ++tj) {
                    int rbase = t * 16 + quad * 4;
                    int col = wn * 64 + tj * 16 + lr;
#pragma unroll
                    for (int r = 0; r < 4; ++r)
                        Cs[(rbase + r) * 132 + col] = acc[ti][tj][r];
                }
            }
        }
        __syncthreads();
        int m = tile_m + p * 32 + erow;
        const float* crow = Cs + erow * 132 + eseg * 16;
        if (MODE == 1) {
            uint64_t hb = (uint64_t)m * N + tile_n + eseg * 16;
#pragma unroll
            for (int c = 0; c < 2; ++c) {
                f32x4 v0 = *(const f32x4*)(crow + c * 8);
                f32x4 v1 = *(const f32x4*)(crow + c * 8 + 4);
                float s[8];
#pragma unroll
                for (int j = 0; j < 4; ++j) {
                    s[j]     = v0[j] * __builtin_amdgcn_rcpf(1.f + __expf(-v0[j]));
                    s[4 + j] = v1[j] * __builtin_amdgcn_rcpf(1.f + __expf(-v1[j]));
                }
                union { __hip_bfloat162 h; unsigned int u; } cv;
                uint4 pk;
                cv.h = __float22bfloat162_rn(float2{s[0], s[1]}); pk.x = cv.u;
                cv.h = __float22bfloat162_rn(float2{s[2], s[3]}); pk.y = cv.u;
                cv.h = __float22bfloat162_rn(float2{s[4], s[5]}); pk.z = cv.u;
                cv.h = __float22bfloat162_rn(float2{s[6], s[7]}); pk.w = cv.u;
                *(uint4*)(Hout + hb + c * 8) = pk;
            }
        } else {
            int grow = rowidx[m];
            float wgt = rw[m];
            uint64_t gb = (uint64_t)grow * D_ + tile_n + eseg * 16;
#pragma unroll
            for (int c = 0; c < 4; ++c) {
                f32x4 v = *(const f32x4*)(crow + c * 4);
                float4 xv = *(const float4*)(x + gb + c * 4);
                float4 o;
                o.x = xv.x + v[0] * wgt;
                o.y = xv.y + v[1] * wgt;
                o.z = xv.z + v[2] * wgt;
                o.w = xv.w + v[3] * wgt;
                *(float4*)(Out + gb + c * 4) = o;
            }
        }
    }
}

// ---------------------------------------------------------------------------
extern "C" void kernel_launch(void* const* d_in, const int* in_sizes, int n_in,
                              void* d_out, int out_size, void* d_ws, size_t ws_size,
                              hipStream_t stream) {
    const float* x  = (const float*)d_in[0];
    // d_in[1] = mask (all-ones; MLP ignores it)
    const float* Wr = (const float*)d_in[2];
    const float* W1 = (const float*)d_in[3];
    const float* W2 = (const float*)d_in[4];
    float* out = (float*)d_out;

    char* ws = (char*)d_ws;
    size_t off = 0;
    auto alloc = [&](size_t bytes) {
        char* p = ws + off;
        off = (off + bytes + 255) & ~(size_t)255;
        return p;
    };
    unsigned short* xb   = (unsigned short*)alloc((size_t)NTOK_ * D_ * 2);
    unsigned short* W1bT = (unsigned short*)alloc((size_t)DFF_ * D_ * 2);
    unsigned short* W2bT = (unsigned short*)alloc((size_t)D_ * DFF_ * 2);
    unsigned short* H    = (unsigned short*)alloc((size_t)M_ * DFF_ * 2);
    float* logits  = (float*)alloc(NTOK_ * 4);
    int*   rank    = (int*)alloc(NTOK_ * 4);
    int*   rowidx  = (int*)alloc(M_ * 4);
    float* rwp     = (float*)alloc(M_ * 4);
    float* bsum    = (float*)alloc(4 * 4);
    int*   segcnt  = (int*)alloc(64 * 4);
    float* lossptr = out + (size_t)NTOK_ * D_;

    (void)hipMemsetAsync(rank, 0, NTOK_ * 4, stream);

    // prep: transposes (8192 blocks) + router (4096 blocks) in one launch
    prep_kernel<<<12288, 256, 0, stream>>>(W1, W1bT, W2, W2bT, x, Wr, logits, xb, out);

    // selection: rank + compact + loss, one cooperative launch
    {
        void* args[] = {(void*)&logits, (void*)&rank, (void*)&bsum, (void*)&segcnt,
                        (void*)&rowidx, (void*)&rwp, (void*)&lossptr};
        (void)hipLaunchCooperativeKernel((void*)select_coop, dim3(512), dim3(256),
                                         args, 0, stream);
    }

    // GEMM1: H[8192][4096] = silu(gather(xb) @ W1); grid x = M-tiles (XCD)
    gemm_bt_kernel<1><<<dim3(M_ / 128, DFF_ / 128), 256, 0, stream>>>(
        xb, W1bT, rowidx, nullptr, nullptr, H, nullptr, D_, DFF_);
    // GEMM2: out[rowidx[m]] = x[rowidx[m]] + (H @ W2)[m] * rw[m]
    gemm_bt_kernel<2><<<dim3(M_ / 128, D_ / 128), 256, 0, stream>>>(
        H, W2bT, rowidx, rwp, x, nullptr, out, DFF_, D_);
}